// Round 1
// baseline (995.568 us; speedup 1.0000x reference)
//
#include <hip/hip_runtime.h>
#include <hip/hip_bf16.h>

typedef __attribute__((ext_vector_type(8))) short short8_t;
typedef __attribute__((ext_vector_type(8))) unsigned short ushort8_t;
typedef __attribute__((ext_vector_type(4))) float f32x4;

#define SCALE 0.125f   // 64^-0.5

__device__ __forceinline__ unsigned short f32_to_bf16_rne(float f) {
  unsigned int u = __float_as_uint(f);
  unsigned int r = 0x7FFFu + ((u >> 16) & 1u);
  return (unsigned short)((u + r) >> 16);
}

// ---------------- cast x (fp32 -> bf16) ----------------
__global__ __launch_bounds__(256) void cast_x_kernel(const float4* __restrict__ in,
                                                     ushort4* __restrict__ out, int n4) {
  int i = blockIdx.x * 256 + threadIdx.x;
  if (i < n4) {
    float4 v = in[i];
    ushort4 o;
    o.x = f32_to_bf16_rne(v.x); o.y = f32_to_bf16_rne(v.y);
    o.z = f32_to_bf16_rne(v.z); o.w = f32_to_bf16_rne(v.w);
    out[i] = o;
  }
}

// ---------------- transpose + cast weights: in R x C fp32 -> out C x R bf16 ----------------
__global__ __launch_bounds__(256) void transpose_cast_kernel(const float* __restrict__ in,
                                                             unsigned short* __restrict__ out,
                                                             int R, int C) {
  __shared__ float tile[32][33];
  int c0 = blockIdx.x * 32, r0 = blockIdx.y * 32;
  int tx = threadIdx.x & 31, ty = threadIdx.x >> 5;  // 32 x 8
  #pragma unroll
  for (int i = ty; i < 32; i += 8)
    tile[i][tx] = in[(long)(r0 + i) * C + c0 + tx];
  __syncthreads();
  #pragma unroll
  for (int i = ty; i < 32; i += 8)
    out[(long)(c0 + i) * R + r0 + tx] = f32_to_bf16_rne(tile[tx][i]);
}

// ---------------- transpose V out of KV buffer: Vt[b][h][d][j] = KV[b*1024+j][768+h*64+d] ----------------
__global__ __launch_bounds__(256) void transpose_v_kernel(const unsigned short* __restrict__ KV,
                                                          unsigned short* __restrict__ Vt) {
  __shared__ unsigned short tile[64][72];
  const int j0 = blockIdx.x * 64, h = blockIdx.y, b = blockIdx.z;
  const int tid = threadIdx.x;
  for (int c = tid; c < 512; c += 256) {
    int j = c >> 3, dp = (c & 7) * 8;
    *(ushort8_t*)&tile[j][dp] =
        *(const ushort8_t*)&KV[(long)(b * 1024 + j0 + j) * 1536 + 768 + h * 64 + dp];
  }
  __syncthreads();
  for (int c = tid; c < 512; c += 256) {
    int d = c >> 3, jp = (c & 7) * 8;
    ushort8_t v;
    #pragma unroll
    for (int t = 0; t < 8; t++) v[t] = tile[jp + t][d];
    *(ushort8_t*)&Vt[((long)(b * 12 + h) * 64 + d) * 1024 + j0 + jp] = v;
  }
}

// ---------------- NT GEMM: C[m,n] = sum_k A[m,k] * B[n,k]  (bf16 in, fp32 acc) ----------------
template <int BM, int BN, bool OUT_F32, bool BIAS>
__global__ __launch_bounds__(256) void gemm_nt(const unsigned short* __restrict__ A, long sAz, int lda,
                                               const unsigned short* __restrict__ B, long sBz, int ldb,
                                               void* __restrict__ Cv, long sCz, int ldc,
                                               const float* __restrict__ bias,
                                               int M, int N, int K) {
  constexpr int BK = 32;
  constexpr int LDT = BK + 8;  // pad -> <=2-way bank aliasing (free)
  __shared__ unsigned short As[BM][LDT];
  __shared__ unsigned short Bs[BN][LDT];
  const int z = blockIdx.z;
  A += (long)z * sAz;
  B += (long)z * sBz;
  const int m0 = blockIdx.y * BM;
  const int n0 = blockIdx.x * BN;
  const int tid = threadIdx.x;
  const int lane = tid & 63;
  const int w = tid >> 6;
  constexpr int WM = BM / 2, WN = BN / 2;
  constexpr int FM = WM / 16, FN = WN / 16;
  const int wr = w >> 1, wc = w & 1;

  f32x4 acc[FM][FN];
  #pragma unroll
  for (int a = 0; a < FM; a++)
    #pragma unroll
    for (int b2 = 0; b2 < FN; b2++) acc[a][b2] = (f32x4){0.f, 0.f, 0.f, 0.f};

  const int rl = lane & 15;
  const int kq = (lane >> 4) * 8;

  for (int k0 = 0; k0 < K; k0 += BK) {
    __syncthreads();
    for (int c = tid; c < BM * (BK / 8); c += 256) {
      int row = c >> 2, kp = (c & 3) * 8;
      *(ushort8_t*)&As[row][kp] = *(const ushort8_t*)&A[(long)(m0 + row) * lda + k0 + kp];
    }
    for (int c = tid; c < BN * (BK / 8); c += 256) {
      int row = c >> 2, kp = (c & 3) * 8;
      *(ushort8_t*)&Bs[row][kp] = *(const ushort8_t*)&B[(long)(n0 + row) * ldb + k0 + kp];
    }
    __syncthreads();
    short8_t af[FM], bfr[FN];
    #pragma unroll
    for (int fm = 0; fm < FM; fm++) af[fm] = *(const short8_t*)&As[wr * WM + fm * 16 + rl][kq];
    #pragma unroll
    for (int fn = 0; fn < FN; fn++) bfr[fn] = *(const short8_t*)&Bs[wc * WN + fn * 16 + rl][kq];
    #pragma unroll
    for (int fm = 0; fm < FM; fm++)
      #pragma unroll
      for (int fn = 0; fn < FN; fn++)
        acc[fm][fn] = __builtin_amdgcn_mfma_f32_16x16x32_bf16(af[fm], bfr[fn], acc[fm][fn], 0, 0, 0);
  }

  const int rq4 = (lane >> 4) * 4;
  #pragma unroll
  for (int fm = 0; fm < FM; fm++)
    #pragma unroll
    for (int fn = 0; fn < FN; fn++)
      #pragma unroll
      for (int j = 0; j < 4; j++) {
        int row = m0 + wr * WM + fm * 16 + rq4 + j;
        int col = n0 + wc * WN + fn * 16 + rl;
        float v = acc[fm][fn][j];
        if (BIAS) v += bias[col];
        if (OUT_F32)
          ((float*)Cv)[(long)z * sCz + (long)row * ldc + col] = v;
        else
          ((unsigned short*)Cv)[(long)z * sCz + (long)row * ldc + col] = f32_to_bf16_rne(v);
      }
}

// ---------------- mix_pre -> softmax -> mix_post, one block per (i) row, all 12 heads ----------------
__device__ __forceinline__ float block_reduce(float v, float* red, bool is_max, int tid) {
  #pragma unroll
  for (int off = 32; off >= 1; off >>= 1) {
    float o = __shfl_xor(v, off);
    v = is_max ? fmaxf(v, o) : (v + o);
  }
  __syncthreads();
  if ((tid & 63) == 0) red[tid >> 6] = v;
  __syncthreads();
  float r0 = red[0], r1 = red[1], r2 = red[2], r3 = red[3];
  return is_max ? fmaxf(fmaxf(r0, r1), fmaxf(r2, r3)) : (r0 + r1 + r2 + r3);
}

__global__ __launch_bounds__(256) void mix_softmax_kernel(const float* __restrict__ dots,
                                                          const float* __restrict__ mix_pre,
                                                          const float* __restrict__ mix_post,
                                                          unsigned short* __restrict__ attnP) {
  __shared__ float sh[1024][13];
  __shared__ float mpre[144], mpost[144];
  __shared__ float red[4];
  const int i = blockIdx.x;
  const int tid = threadIdx.x;
  if (tid < 144) { mpre[tid] = mix_pre[tid]; mpost[tid] = mix_post[tid]; }
  for (int h = 0; h < 12; h++)
    for (int j = tid; j < 1024; j += 256)
      sh[j][h] = dots[(long)h * 1048576 + (long)i * 1024 + j];
  __syncthreads();

  float acc[12][4];
  #pragma unroll
  for (int g2 = 0; g2 < 12; g2++)
    #pragma unroll
    for (int k = 0; k < 4; k++) acc[g2][k] = 0.f;

  for (int g = 0; g < 12; g++) {
    float mg[4];
    float lmax = -1e30f;
    #pragma unroll
    for (int k = 0; k < 4; k++) {
      int j = tid + k * 256;
      float s = 0.f;
      #pragma unroll
      for (int h = 0; h < 12; h++) s += mpre[h * 12 + g] * sh[j][h];
      mg[k] = s * SCALE;
      lmax = fmaxf(lmax, mg[k]);
    }
    float m = block_reduce(lmax, red, true, tid);
    float lsum = 0.f;
    #pragma unroll
    for (int k = 0; k < 4; k++) {
      mg[k] = __expf(mg[k] - m);
      lsum += mg[k];
    }
    float l = block_reduce(lsum, red, false, tid);
    float inv = 1.0f / l;
    #pragma unroll
    for (int k = 0; k < 4; k++) {
      float p = mg[k] * inv;
      #pragma unroll
      for (int g2 = 0; g2 < 12; g2++) acc[g2][k] += mpost[g * 12 + g2] * p;
    }
  }
  #pragma unroll
  for (int g2 = 0; g2 < 12; g2++)
    #pragma unroll
    for (int k = 0; k < 4; k++) {
      int j = tid + k * 256;
      attnP[(long)g2 * 1048576 + (long)i * 1024 + j] = f32_to_bf16_rne(acc[g2][k]);
    }
}

// ---------------- host launch ----------------
extern "C" void kernel_launch(void* const* d_in, const int* in_sizes, int n_in,
                              void* d_out, int out_size, void* d_ws, size_t ws_size,
                              hipStream_t stream) {
  const float* x        = (const float*)d_in[0];
  const float* W_q      = (const float*)d_in[1];
  const float* W_kv     = (const float*)d_in[2];
  const float* mix_pre  = (const float*)d_in[3];
  const float* mix_post = (const float*)d_in[4];
  const float* W_out    = (const float*)d_in[5];
  const float* b_out    = (const float*)d_in[6];
  float* out = (float*)d_out;

  char* p = (char*)d_ws;
  auto alloc = [&](size_t bytes) { char* r = p; p += (bytes + 255) & ~(size_t)255; return r; };
  unsigned short* xb    = (unsigned short*)alloc(8192ull * 768 * 2);
  unsigned short* WqT   = (unsigned short*)alloc(768ull * 768 * 2);
  unsigned short* WkvT  = (unsigned short*)alloc(1536ull * 768 * 2);
  unsigned short* WoutT = (unsigned short*)alloc(768ull * 768 * 2);
  unsigned short* Qb    = (unsigned short*)alloc(8192ull * 768 * 2);
  unsigned short* KVb   = (unsigned short*)alloc(8192ull * 1536 * 2);
  unsigned short* Vt    = (unsigned short*)alloc(8ull * 12 * 64 * 1024 * 2);
  unsigned short* AO    = (unsigned short*)alloc(8192ull * 768 * 2);
  float*          dots  = (float*)alloc(12ull * 1024 * 1024 * 4);
  unsigned short* attnP = (unsigned short*)alloc(12ull * 1024 * 1024 * 2);

  // 1) casts / transposes
  cast_x_kernel<<<6144, 256, 0, stream>>>((const float4*)x, (ushort4*)xb, 8192 * 768 / 4);
  transpose_cast_kernel<<<dim3(24, 24), 256, 0, stream>>>(W_q, WqT, 768, 768);
  transpose_cast_kernel<<<dim3(48, 24), 256, 0, stream>>>(W_kv, WkvT, 768, 1536);
  transpose_cast_kernel<<<dim3(24, 24), 256, 0, stream>>>(W_out, WoutT, 768, 768);

  // 2) projections: Q = xb @ WqT^T, KV = xb @ WkvT^T
  gemm_nt<128, 128, false, false><<<dim3(6, 64, 1), 256, 0, stream>>>(
      xb, 0, 768, WqT, 0, 768, Qb, 0, 768, nullptr, 8192, 768, 768);
  gemm_nt<128, 128, false, false><<<dim3(12, 64, 1), 256, 0, stream>>>(
      xb, 0, 768, WkvT, 0, 768, KVb, 0, 1536, nullptr, 8192, 1536, 768);

  // 3) V transpose for NT PV gemm
  transpose_v_kernel<<<dim3(16, 12, 8), 256, 0, stream>>>(KVb, Vt);

  // 4) per-batch attention (scratch dots/attnP reused; stream-serialized)
  for (int b = 0; b < 8; b++) {
    // dots[h,i,j] = Q_bh @ K_bh^T   (raw, scale folded into mix stage)
    gemm_nt<128, 128, true, false><<<dim3(8, 8, 12), 256, 0, stream>>>(
        Qb + (long)b * 1024 * 768, 64, 768,
        KVb + (long)b * 1024 * 1536, 64, 1536,
        dots, 1048576, 1024, nullptr, 1024, 1024, 64);
    mix_softmax_kernel<<<1024, 256, 0, stream>>>(dots, mix_pre, mix_post, attnP);
    // AO[b, i, g*64+d] = attnP[g] @ Vt[b,g]^T
    gemm_nt<128, 64, false, false><<<dim3(1, 8, 12), 256, 0, stream>>>(
        attnP, 1048576, 1024,
        Vt + (long)b * 12 * 65536, 65536, 1024,
        AO + (long)b * 1024 * 768, 64, 768, nullptr, 1024, 64, 1024);
  }

  // 5) out = AO @ WoutT^T + b_out  (fp32 out)
  gemm_nt<128, 128, true, true><<<dim3(6, 64, 1), 256, 0, stream>>>(
      AO, 0, 768, WoutT, 0, 768, out, 0, 768, b_out, 8192, 768, 768);
}

// Round 2
// 667.595 us; speedup vs baseline: 1.4913x; 1.4913x over previous
//
#include <hip/hip_runtime.h>
#include <hip/hip_bf16.h>

typedef __attribute__((ext_vector_type(8))) short short8_t;
typedef __attribute__((ext_vector_type(8))) unsigned short ushort8_t;
typedef __attribute__((ext_vector_type(4))) float f32x4;

#define SCALE 0.125f   // 64^-0.5

__device__ __forceinline__ unsigned short f32_to_bf16_rne(float f) {
  unsigned int u = __float_as_uint(f);
  unsigned int r = 0x7FFFu + ((u >> 16) & 1u);
  return (unsigned short)((u + r) >> 16);
}

// ---------------- cast x (fp32 -> bf16) ----------------
__global__ __launch_bounds__(256) void cast_x_kernel(const float4* __restrict__ in,
                                                     ushort4* __restrict__ out, int n4) {
  int i = blockIdx.x * 256 + threadIdx.x;
  if (i < n4) {
    float4 v = in[i];
    ushort4 o;
    o.x = f32_to_bf16_rne(v.x); o.y = f32_to_bf16_rne(v.y);
    o.z = f32_to_bf16_rne(v.z); o.w = f32_to_bf16_rne(v.w);
    out[i] = o;
  }
}

// ---------------- transpose + cast weights: in R x C fp32 -> out C x R bf16 ----------------
__global__ __launch_bounds__(256) void transpose_cast_kernel(const float* __restrict__ in,
                                                             unsigned short* __restrict__ out,
                                                             int R, int C) {
  __shared__ float tile[32][33];
  int c0 = blockIdx.x * 32, r0 = blockIdx.y * 32;
  int tx = threadIdx.x & 31, ty = threadIdx.x >> 5;  // 32 x 8
  #pragma unroll
  for (int i = ty; i < 32; i += 8)
    tile[i][tx] = in[(long)(r0 + i) * C + c0 + tx];
  __syncthreads();
  #pragma unroll
  for (int i = ty; i < 32; i += 8)
    out[(long)(c0 + i) * R + r0 + tx] = f32_to_bf16_rne(tile[tx][i]);
}

// ---------------- transpose V out of KV buffer: Vt[b][h][d][j] = KV[b*1024+j][768+h*64+d] ----------------
__global__ __launch_bounds__(256) void transpose_v_kernel(const unsigned short* __restrict__ KV,
                                                          unsigned short* __restrict__ Vt) {
  __shared__ unsigned short tile[64][72];
  const int j0 = blockIdx.x * 64, h = blockIdx.y, b = blockIdx.z;
  const int tid = threadIdx.x;
  for (int c = tid; c < 512; c += 256) {
    int j = c >> 3, dp = (c & 7) * 8;
    *(ushort8_t*)&tile[j][dp] =
        *(const ushort8_t*)&KV[(long)(b * 1024 + j0 + j) * 1536 + 768 + h * 64 + dp];
  }
  __syncthreads();
  for (int c = tid; c < 512; c += 256) {
    int d = c >> 3, jp = (c & 7) * 8;
    ushort8_t v;
    #pragma unroll
    for (int t = 0; t < 8; t++) v[t] = tile[jp + t][d];
    *(ushort8_t*)&Vt[((long)(b * 12 + h) * 64 + d) * 1024 + j0 + jp] = v;
  }
}

// ---------------- NT GEMM: C[m,n] = sum_k A[m,k] * B[n,k]  (bf16 in, fp32 acc) ----------------
// z decomposed as z1 = z/zdiv, z2 = z%zdiv; offsets = z1*s?z + z2*s?z2.
template <int BM, int BN, bool OUT_F32, bool BIAS>
__global__ __launch_bounds__(256) void gemm_nt(const unsigned short* __restrict__ A, long sAz, long sAz2, int lda,
                                               const unsigned short* __restrict__ B, long sBz, long sBz2, int ldb,
                                               void* __restrict__ Cv, long sCz, long sCz2, int ldc,
                                               const float* __restrict__ bias, int zdiv,
                                               int M, int N, int K) {
  constexpr int BK = 32;
  constexpr int LDT = BK + 8;  // pad -> <=2-way bank aliasing (free)
  __shared__ unsigned short As[BM][LDT];
  __shared__ unsigned short Bs[BN][LDT];
  const int z = blockIdx.z;
  const int z1 = z / zdiv, z2 = z - z1 * zdiv;
  A += z1 * sAz + z2 * sAz2;
  B += z1 * sBz + z2 * sBz2;
  const long coff = z1 * sCz + z2 * sCz2;
  const int m0 = blockIdx.y * BM;
  const int n0 = blockIdx.x * BN;
  const int tid = threadIdx.x;
  const int lane = tid & 63;
  const int w = tid >> 6;
  constexpr int WM = BM / 2, WN = BN / 2;
  constexpr int FM = WM / 16, FN = WN / 16;
  const int wr = w >> 1, wc = w & 1;

  f32x4 acc[FM][FN];
  #pragma unroll
  for (int a = 0; a < FM; a++)
    #pragma unroll
    for (int b2 = 0; b2 < FN; b2++) acc[a][b2] = (f32x4){0.f, 0.f, 0.f, 0.f};

  const int rl = lane & 15;
  const int kq = (lane >> 4) * 8;

  for (int k0 = 0; k0 < K; k0 += BK) {
    __syncthreads();
    for (int c = tid; c < BM * (BK / 8); c += 256) {
      int row = c >> 2, kp = (c & 3) * 8;
      *(ushort8_t*)&As[row][kp] = *(const ushort8_t*)&A[(long)(m0 + row) * lda + k0 + kp];
    }
    for (int c = tid; c < BN * (BK / 8); c += 256) {
      int row = c >> 2, kp = (c & 3) * 8;
      *(ushort8_t*)&Bs[row][kp] = *(const ushort8_t*)&B[(long)(n0 + row) * ldb + k0 + kp];
    }
    __syncthreads();
    short8_t af[FM], bfr[FN];
    #pragma unroll
    for (int fm = 0; fm < FM; fm++) af[fm] = *(const short8_t*)&As[wr * WM + fm * 16 + rl][kq];
    #pragma unroll
    for (int fn = 0; fn < FN; fn++) bfr[fn] = *(const short8_t*)&Bs[wc * WN + fn * 16 + rl][kq];
    #pragma unroll
    for (int fm = 0; fm < FM; fm++)
      #pragma unroll
      for (int fn = 0; fn < FN; fn++)
        acc[fm][fn] = __builtin_amdgcn_mfma_f32_16x16x32_bf16(af[fm], bfr[fn], acc[fm][fn], 0, 0, 0);
  }

  const int rq4 = (lane >> 4) * 4;
  #pragma unroll
  for (int fm = 0; fm < FM; fm++)
    #pragma unroll
    for (int fn = 0; fn < FN; fn++)
      #pragma unroll
      for (int j = 0; j < 4; j++) {
        int row = m0 + wr * WM + fm * 16 + rq4 + j;
        int col = n0 + wc * WN + fn * 16 + rl;
        float v = acc[fm][fn][j];
        if (BIAS) v += bias[col];
        if (OUT_F32)
          ((float*)Cv)[coff + (long)row * ldc + col] = v;
        else
          ((unsigned short*)Cv)[coff + (long)row * ldc + col] = f32_to_bf16_rne(v);
      }
}

// ---------------- mix_pre -> softmax -> mix_post ----------------
// One block per row i. Thread owns j = tid*4 .. tid*4+3 (float4 loads).
// All 12 output heads reduced with 2 batched cross-wave reduces (3 syncs total).
__global__ __launch_bounds__(256) void mix_softmax_kernel(const float* __restrict__ dots,
                                                          const float* __restrict__ mix_pre,
                                                          const float* __restrict__ mix_post,
                                                          unsigned short* __restrict__ attnP) {
  __shared__ float mpre[144], mpost[144];
  __shared__ float redm[12][4], reds[12][4];
  const int i = blockIdx.x;
  const int tid = threadIdx.x;
  if (tid < 144) { mpre[tid] = mix_pre[tid] * SCALE; mpost[tid] = mix_post[tid]; }
  __syncthreads();

  const int j0 = tid * 4;
  const long rowbase = (long)i * 1024 + j0;

  float s[12][4];
  #pragma unroll
  for (int h = 0; h < 12; h++) {
    float4 v = *(const float4*)&dots[(long)h * 1048576 + rowbase];
    s[h][0] = v.x; s[h][1] = v.y; s[h][2] = v.z; s[h][3] = v.w;
  }

  // mixed logits (scale folded into mpre)
  float mg[12][4];
  float lmax[12];
  #pragma unroll
  for (int g = 0; g < 12; g++) {
    #pragma unroll
    for (int k = 0; k < 4; k++) {
      float a = 0.f;
      #pragma unroll
      for (int h = 0; h < 12; h++) a += mpre[h * 12 + g] * s[h][k];
      mg[g][k] = a;
    }
    lmax[g] = fmaxf(fmaxf(mg[g][0], mg[g][1]), fmaxf(mg[g][2], mg[g][3]));
  }

  // batched max reduce: 12 heads through one shuffle pass, one sync
  #pragma unroll
  for (int off = 32; off >= 1; off >>= 1)
    #pragma unroll
    for (int g = 0; g < 12; g++)
      lmax[g] = fmaxf(lmax[g], __shfl_xor(lmax[g], off));
  if ((tid & 63) == 0)
    #pragma unroll
    for (int g = 0; g < 12; g++) redm[g][tid >> 6] = lmax[g];
  __syncthreads();

  float lsum[12];
  #pragma unroll
  for (int g = 0; g < 12; g++) {
    float m = fmaxf(fmaxf(redm[g][0], redm[g][1]), fmaxf(redm[g][2], redm[g][3]));
    float ls = 0.f;
    #pragma unroll
    for (int k = 0; k < 4; k++) {
      mg[g][k] = __expf(mg[g][k] - m);
      ls += mg[g][k];
    }
    lsum[g] = ls;
  }

  // batched sum reduce
  #pragma unroll
  for (int off = 32; off >= 1; off >>= 1)
    #pragma unroll
    for (int g = 0; g < 12; g++)
      lsum[g] += __shfl_xor(lsum[g], off);
  if ((tid & 63) == 0)
    #pragma unroll
    for (int g = 0; g < 12; g++) reds[g][tid >> 6] = lsum[g];
  __syncthreads();

  #pragma unroll
  for (int g = 0; g < 12; g++) {
    float inv = 1.f / (reds[g][0] + reds[g][1] + reds[g][2] + reds[g][3]);
    #pragma unroll
    for (int k = 0; k < 4; k++) mg[g][k] *= inv;
  }

  // post-softmax talking heads + store (bf16)
  #pragma unroll
  for (int g2 = 0; g2 < 12; g2++) {
    float o0 = 0.f, o1 = 0.f, o2 = 0.f, o3 = 0.f;
    #pragma unroll
    for (int g = 0; g < 12; g++) {
      float wgt = mpost[g * 12 + g2];
      o0 += wgt * mg[g][0]; o1 += wgt * mg[g][1];
      o2 += wgt * mg[g][2]; o3 += wgt * mg[g][3];
    }
    ushort4 ov;
    ov.x = f32_to_bf16_rne(o0); ov.y = f32_to_bf16_rne(o1);
    ov.z = f32_to_bf16_rne(o2); ov.w = f32_to_bf16_rne(o3);
    *(ushort4*)&attnP[(long)g2 * 1048576 + rowbase] = ov;
  }
}

// ---------------- host launch ----------------
extern "C" void kernel_launch(void* const* d_in, const int* in_sizes, int n_in,
                              void* d_out, int out_size, void* d_ws, size_t ws_size,
                              hipStream_t stream) {
  const float* x        = (const float*)d_in[0];
  const float* W_q      = (const float*)d_in[1];
  const float* W_kv     = (const float*)d_in[2];
  const float* mix_pre  = (const float*)d_in[3];
  const float* mix_post = (const float*)d_in[4];
  const float* W_out    = (const float*)d_in[5];
  const float* b_out    = (const float*)d_in[6];
  float* out = (float*)d_out;

  char* p = (char*)d_ws;
  auto alloc = [&](size_t bytes) { char* r = p; p += (bytes + 255) & ~(size_t)255; return r; };
  unsigned short* xb    = (unsigned short*)alloc(8192ull * 768 * 2);
  unsigned short* WqT   = (unsigned short*)alloc(768ull * 768 * 2);
  unsigned short* WkvT  = (unsigned short*)alloc(1536ull * 768 * 2);
  unsigned short* WoutT = (unsigned short*)alloc(768ull * 768 * 2);
  unsigned short* Qb    = (unsigned short*)alloc(8192ull * 768 * 2);
  unsigned short* KVb   = (unsigned short*)alloc(8192ull * 1536 * 2);
  unsigned short* Vt    = (unsigned short*)alloc(8ull * 12 * 64 * 1024 * 2);
  unsigned short* AO    = (unsigned short*)alloc(8192ull * 768 * 2);
  float*          dots  = (float*)alloc(12ull * 1024 * 1024 * 4);

  // attnP: all-b (201 MB, enables single batched PV dispatch) if ws allows,
  // else single-b (25 MB) with per-b PV dispatches. ws_size is constant ->
  // deterministic path selection.
  const bool big = ws_size >= 333000000ull;
  unsigned short* attnP = (unsigned short*)alloc(big ? 8ull * 12 * 1024 * 1024 * 2
                                                     : 12ull * 1024 * 1024 * 2);

  // 1) casts / transposes
  cast_x_kernel<<<6144, 256, 0, stream>>>((const float4*)x, (ushort4*)xb, 8192 * 768 / 4);
  transpose_cast_kernel<<<dim3(24, 24), 256, 0, stream>>>(W_q, WqT, 768, 768);
  transpose_cast_kernel<<<dim3(48, 24), 256, 0, stream>>>(W_kv, WkvT, 768, 1536);
  transpose_cast_kernel<<<dim3(24, 24), 256, 0, stream>>>(W_out, WoutT, 768, 768);

  // 2) projections
  gemm_nt<128, 128, false, false><<<dim3(6, 64, 1), 256, 0, stream>>>(
      xb, 0, 0, 768, WqT, 0, 0, 768, Qb, 0, 0, 768, nullptr, 1, 8192, 768, 768);
  gemm_nt<128, 128, false, false><<<dim3(12, 64, 1), 256, 0, stream>>>(
      xb, 0, 0, 768, WkvT, 0, 0, 768, KVb, 0, 0, 1536, nullptr, 1, 8192, 1536, 768);

  // 3) V transpose for NT PV gemm
  transpose_v_kernel<<<dim3(16, 12, 8), 256, 0, stream>>>(KVb, Vt);

  // 4) per-batch QK^T + mix/softmax (dots scratch reused per b)
  for (int b = 0; b < 8; b++) {
    gemm_nt<128, 128, true, false><<<dim3(8, 8, 12), 256, 0, stream>>>(
        Qb + (long)b * 1024 * 768, 64, 0, 768,
        KVb + (long)b * 1024 * 1536, 64, 0, 1536,
        dots, 1048576, 0, 1024, nullptr, 1, 1024, 1024, 64);
    mix_softmax_kernel<<<1024, 256, 0, stream>>>(
        dots, mix_pre, mix_post, attnP + (big ? (long)b * 12 * 1048576 : 0));
    if (!big) {
      gemm_nt<128, 64, false, false><<<dim3(1, 8, 12), 256, 0, stream>>>(
          attnP, 1048576, 0, 1024,
          Vt + (long)b * 12 * 65536, 65536, 0, 1024,
          AO + (long)b * 1024 * 768, 64, 0, 768, nullptr, 1, 1024, 64, 1024);
    }
  }
  if (big) {
    // single PV dispatch over all (b,g): z = b*12+g, 768 blocks
    gemm_nt<128, 64, false, false><<<dim3(1, 8, 96), 256, 0, stream>>>(
        attnP, 12ll * 1048576, 1048576, 1024,
        Vt, 12ll * 65536, 65536, 1024,
        AO, 786432, 64, 768, nullptr, 12, 1024, 64, 1024);
  }

  // 5) out = AO @ WoutT^T + b_out (fp32 out)
  gemm_nt<128, 128, true, true><<<dim3(6, 64, 1), 256, 0, stream>>>(
      AO, 0, 0, 768, WoutT, 0, 0, 768, out, 0, 0, 768, b_out, 1, 8192, 768, 768);
}